// Round 5
// baseline (235.310 us; speedup 1.0000x reference)
//
#include <hip/hip_runtime.h>
#include <math.h>

#define NB    16        // batch
#define NC    25        // channels
#define HW    65536     // 256*256
#define CHW   (NC * HW)
#define EPSF  1e-8f
#define TPB   256       // threads per block
#define BPI   64        // blocks per image; slab = 1024 px = 1 float4/thread
#define SLAB  1024

union F4 { float4 v; float a[4]; };

__device__ __forceinline__ float wave_reduce(float v) {
#pragma unroll
    for (int o = 32; o > 0; o >>= 1) v += __shfl_down(v, o, 64);
    return v;
}

// ---------------- Kernel A: channels 0..4 (obj BCE, F1 counts, size/offset L1)
// Low VGPR (~60), no spills, 6 waves/EU floor. 42 MB of the 210 MB.
__global__ __launch_bounds__(TPB, 6) void yolo_head(const float* __restrict__ outputs,
                                                    const float* __restrict__ labels,
                                                    float* __restrict__ acc) {
    const int b    = blockIdx.x / BPI;
    const int slab = blockIdx.x % BPI;
    const size_t px = (size_t)b * CHW + slab * SLAB + threadIdx.x * 4;
    const float* op = outputs + px;
    const float* lp = labels  + px;

    F4 x, y;
    x.v = *(const float4*)op;
    y.v = *(const float4*)lp;

    float obj = 0.f, szs = 0.f, offs = 0.f;
    float tp = 0.f, fp = 0.f, fn = 0.f;

#pragma unroll
    for (int i = 0; i < 4; ++i) {
        float xv = x.a[i], yv = y.a[i];
        float xc = fminf(fmaxf(xv,        EPSF), 1.0f - EPSF);
        float x1 = fminf(fmaxf(1.0f - xv, EPSF), 1.0f - EPSF);
        obj += -yv * (1.0f - xc) * __logf(xc)
               - (1.0f - yv) * (1.0f - x1) * __logf(x1);
        float p  = (xv > 0.5f) ? 1.f : 0.f;
        float yt = (yv > 0.5f) ? 1.f : 0.f;
        tp += p * yt;
        fp += p * (1.f - yt);
        fn += (1.f - p) * yt;
    }

#pragma unroll
    for (int c = 1; c <= 4; ++c) {
        F4 o, l;
        o.v = *(const float4*)(op + (size_t)c * HW);
        l.v = *(const float4*)(lp + (size_t)c * HW);
        float s = 0.f;
#pragma unroll
        for (int i = 0; i < 4; ++i) s += y.a[i] * fabsf(o.a[i] - l.a[i]);
        if (c <= 2) szs += s; else offs += s;
    }

    obj = wave_reduce(obj);
    szs = wave_reduce(szs);
    offs = wave_reduce(offs);
    tp  = wave_reduce(tp);
    fp  = wave_reduce(fp);
    fn  = wave_reduce(fn);

    __shared__ float sm[TPB / 64][6];
    const int lane = threadIdx.x & 63, wv = threadIdx.x >> 6;
    if (lane == 0) {
        sm[wv][0] = obj; sm[wv][1] = szs; sm[wv][2] = offs;
        sm[wv][3] = tp;  sm[wv][4] = fp;  sm[wv][5] = fn;
    }
    __syncthreads();
    if (threadIdx.x < 6) {
        float s = 0.f;
#pragma unroll
        for (int w = 0; w < TPB / 64; ++w) s += sm[w][threadIdx.x];
        if (threadIdx.x < 3) atomicAdd(&acc[threadIdx.x], s);                  // obj,szs,offs
        else                 atomicAdd(&acc[4 + 3 * b + (threadIdx.x - 3)], s); // tp,fp,fn
    }
}

// ---------------- Kernel B: channels 5..24 argmax + class loss.
// Only 2 advancing streams (l[c], o[c]) + one y read -> copy-like shape,
// ~46 VGPR, depth-1 explicit channel prefetch ring. 172 MB of the 210 MB.
__global__ __launch_bounds__(TPB, 6) void yolo_argmax(const float* __restrict__ outputs,
                                                      const float* __restrict__ labels,
                                                      float* __restrict__ acc) {
    const int b    = blockIdx.x / BPI;
    const int slab = blockIdx.x % BPI;
    const size_t px = (size_t)b * CHW + slab * SLAB + threadIdx.x * 4;
    const float* op = outputs + px;
    const float* lp = labels  + px;

    F4 y;
    y.v = *(const float4*)lp;          // y = labels channel 0

    F4 vmax, vout;
#pragma unroll
    for (int i = 0; i < 4; ++i) { vmax.a[i] = -1.0f; vout.a[i] = 0.0f; }

    // prologue: c=5 in flight
    F4 lc, oc;
    lc.v = *(const float4*)(lp + (size_t)5 * HW);
    oc.v = *(const float4*)(op + (size_t)5 * HW);

#pragma unroll
    for (int c = 5; c < NC - 1; ++c) {
        F4 ln, on;                     // issue c+1 before consuming c
        ln.v = *(const float4*)(lp + (size_t)(c + 1) * HW);
        on.v = *(const float4*)(op + (size_t)(c + 1) * HW);
#pragma unroll
        for (int i = 0; i < 4; ++i) {
            if (lc.a[i] > vmax.a[i]) { vmax.a[i] = lc.a[i]; vout.a[i] = oc.a[i]; }
        }
        lc = ln; oc = on;
    }
#pragma unroll
    for (int i = 0; i < 4; ++i) {      // epilogue: consume c=24
        if (lc.a[i] > vmax.a[i]) { vmax.a[i] = lc.a[i]; vout.a[i] = oc.a[i]; }
    }

    float cls = 0.f;
#pragma unroll
    for (int i = 0; i < 4; ++i) cls += y.a[i] * (-vout.a[i]);

    cls = wave_reduce(cls);
    __shared__ float sm[TPB / 64];
    const int lane = threadIdx.x & 63, wv = threadIdx.x >> 6;
    if (lane == 0) sm[wv] = cls;
    __syncthreads();
    if (threadIdx.x == 0) {
        float s = 0.f;
#pragma unroll
        for (int w = 0; w < TPB / 64; ++w) s += sm[w];
        atomicAdd(&acc[3], s);
    }
}

__global__ void yolo_fin(const float* __restrict__ acc, float* __restrict__ out) {
    if (threadIdx.x == 0) {
        float obj = acc[0];
        float sz  = 0.1f * acc[1];
        float off = 0.1f * acc[2];
        float cls = acc[3];
        float f1 = 0.f;
        for (int b = 0; b < NB; ++b) {
            float tp = acc[4 + 3 * b], fp = acc[5 + 3 * b], fn = acc[6 + 3 * b];
            float den = 2.f * tp + fp + fn;
            f1 += (den > 0.f) ? (2.f * tp) / fmaxf(den, 1.f) : 0.f;
        }
        f1 *= (1.0f / NB);
        out[0] = obj + sz + off + cls;
        out[1] = f1;
        out[2] = obj;
        out[3] = sz;
        out[4] = off;
        out[5] = cls;
    }
}

extern "C" void kernel_launch(void* const* d_in, const int* in_sizes, int n_in,
                              void* d_out, int out_size, void* d_ws, size_t ws_size,
                              hipStream_t stream) {
    const float* outputs = (const float*)d_in[0];
    const float* labels  = (const float*)d_in[1];
    float* acc = (float*)d_ws;   // [0]obj [1]szs [2]offs [3]cls [4+3b..] tp,fp,fn

    hipMemsetAsync(acc, 0, (4 + 3 * NB) * sizeof(float), stream);
    yolo_head  <<<NB * BPI, TPB, 0, stream>>>(outputs, labels, acc);
    yolo_argmax<<<NB * BPI, TPB, 0, stream>>>(outputs, labels, acc);
    yolo_fin<<<1, 64, 0, stream>>>(acc, (float*)d_out);
}

// Round 6
// 223.875 us; speedup vs baseline: 1.0511x; 1.0511x over previous
//
#include <hip/hip_runtime.h>
#include <math.h>

#define NB    16        // batch
#define NC    25        // channels
#define HW    65536     // 256*256
#define CHW   (NC * HW)
#define EPSF  1e-8f
#define TPB   256       // threads per block
#define BPI   64        // blocks per image; slab = 1024 px = 1 float4/thread
#define SLAB  1024
#define RING  4         // channel prefetch ring depth (argmax phase)

union F4 { float4 v; float a[4]; };

__device__ __forceinline__ float wave_reduce(float v) {
#pragma unroll
    for (int o = 32; o > 0; o >>= 1) v += __shfl_down(v, o, 64);
    return v;
}

// Monolithic, deep-MLP version. R5 evidence: compiler honors source-level
// prefetch rings exactly (VGPR=32 == depth-1 ring as written) and every
// config with ~2KB/wave in flight pins at ~10.6 B/cyc/CU effective. This
// kernel keeps 18 loads in flight through the head phase and a depth-4
// ring (3-4 outstanding) through the 20 argmax channels. All ring indices
// compile-time (full unroll) -> registers, not scratch.
// __launch_bounds__(256,4): VGPR cap 128 > ~100 needed -> no spills.
__global__ __launch_bounds__(TPB, 4) void yolo_main(const float* __restrict__ outputs,
                                                    const float* __restrict__ labels,
                                                    float* __restrict__ acc) {
    const int b    = blockIdx.x / BPI;
    const int slab = blockIdx.x % BPI;
    const size_t px = (size_t)b * CHW + slab * SLAB + threadIdx.x * 4;
    const float* op = outputs + px;
    const float* lp = labels  + px;

    // ---- issue head loads (c=0..4) and argmax ring prologue (c=5..8): 18 in flight
    F4 x0, y0, o1, l1, o2, l2, o3, l3, o4, l4;
    x0.v = *(const float4*)(op);
    y0.v = *(const float4*)(lp);
    o1.v = *(const float4*)(op + (size_t)1 * HW);
    l1.v = *(const float4*)(lp + (size_t)1 * HW);
    o2.v = *(const float4*)(op + (size_t)2 * HW);
    l2.v = *(const float4*)(lp + (size_t)2 * HW);
    o3.v = *(const float4*)(op + (size_t)3 * HW);
    l3.v = *(const float4*)(lp + (size_t)3 * HW);
    o4.v = *(const float4*)(op + (size_t)4 * HW);
    l4.v = *(const float4*)(lp + (size_t)4 * HW);

    F4 lring[RING], oring[RING];
#pragma unroll
    for (int k = 0; k < RING; ++k) {
        lring[k].v = *(const float4*)(lp + (size_t)(5 + k) * HW);
        oring[k].v = *(const float4*)(op + (size_t)(5 + k) * HW);
    }

    float obj = 0.f, szs = 0.f, offs = 0.f, cls = 0.f;
    float tp = 0.f, fp = 0.f, fn = 0.f;

    // ---- c = 0: objectness BCE + F1 counts
#pragma unroll
    for (int i = 0; i < 4; ++i) {
        float xv = x0.a[i], yv = y0.a[i];
        float xc = fminf(fmaxf(xv,        EPSF), 1.0f - EPSF);
        float x1 = fminf(fmaxf(1.0f - xv, EPSF), 1.0f - EPSF);
        obj += -yv * (1.0f - xc) * __logf(xc)
               - (1.0f - yv) * (1.0f - x1) * __logf(x1);
        float p  = (xv > 0.5f) ? 1.f : 0.f;
        float yt = (yv > 0.5f) ? 1.f : 0.f;
        tp += p * yt;
        fp += p * (1.f - yt);
        fn += (1.f - p) * yt;
    }

    // ---- c = 1..4: size / offset L1 (masked by y)
#pragma unroll
    for (int i = 0; i < 4; ++i) {
        szs  += y0.a[i] * fabsf(o1.a[i] - l1.a[i]);
        szs  += y0.a[i] * fabsf(o2.a[i] - l2.a[i]);
        offs += y0.a[i] * fabsf(o3.a[i] - l3.a[i]);
        offs += y0.a[i] * fabsf(o4.a[i] - l4.a[i]);
    }

    // ---- c = 5..24: argmax(labels) carrying outputs; depth-4 ring.
    // strict > reproduces argmax first-index tie-break; ring preserves order.
    F4 vmax, vout;
#pragma unroll
    for (int i = 0; i < 4; ++i) { vmax.a[i] = -1.0f; vout.a[i] = 0.0f; }

#pragma unroll
    for (int c = 5; c < NC; ++c) {
        const int s = (c - 5) & (RING - 1);   // compile-time after unroll
#pragma unroll
        for (int i = 0; i < 4; ++i) {
            if (lring[s].a[i] > vmax.a[i]) { vmax.a[i] = lring[s].a[i]; vout.a[i] = oring[s].a[i]; }
        }
        const int cn = c + RING;
        if (cn < NC) {                        // compile-time predicate
            lring[s].v = *(const float4*)(lp + (size_t)cn * HW);
            oring[s].v = *(const float4*)(op + (size_t)cn * HW);
        }
    }
#pragma unroll
    for (int i = 0; i < 4; ++i) cls += y0.a[i] * (-vout.a[i]);

    // ---- block reduction: 7 values
    obj  = wave_reduce(obj);
    szs  = wave_reduce(szs);
    offs = wave_reduce(offs);
    cls  = wave_reduce(cls);
    tp   = wave_reduce(tp);
    fp   = wave_reduce(fp);
    fn   = wave_reduce(fn);

    __shared__ float sm[TPB / 64][7];
    const int lane = threadIdx.x & 63, wv = threadIdx.x >> 6;
    if (lane == 0) {
        sm[wv][0] = obj;  sm[wv][1] = szs; sm[wv][2] = offs;
        sm[wv][3] = cls;  sm[wv][4] = tp;  sm[wv][5] = fp;  sm[wv][6] = fn;
    }
    __syncthreads();
    if (threadIdx.x < 7) {
        float s = 0.f;
#pragma unroll
        for (int w = 0; w < TPB / 64; ++w) s += sm[w][threadIdx.x];
        if (threadIdx.x < 4) atomicAdd(&acc[threadIdx.x], s);
        else                 atomicAdd(&acc[4 + 3 * b + (threadIdx.x - 4)], s);
    }
}

__global__ void yolo_fin(const float* __restrict__ acc, float* __restrict__ out) {
    if (threadIdx.x == 0) {
        float obj = acc[0];
        float sz  = 0.1f * acc[1];
        float off = 0.1f * acc[2];
        float cls = acc[3];
        float f1 = 0.f;
        for (int b = 0; b < NB; ++b) {
            float tp = acc[4 + 3 * b], fp = acc[5 + 3 * b], fn = acc[6 + 3 * b];
            float den = 2.f * tp + fp + fn;
            f1 += (den > 0.f) ? (2.f * tp) / fmaxf(den, 1.f) : 0.f;
        }
        f1 *= (1.0f / NB);
        out[0] = obj + sz + off + cls;
        out[1] = f1;
        out[2] = obj;
        out[3] = sz;
        out[4] = off;
        out[5] = cls;
    }
}

extern "C" void kernel_launch(void* const* d_in, const int* in_sizes, int n_in,
                              void* d_out, int out_size, void* d_ws, size_t ws_size,
                              hipStream_t stream) {
    const float* outputs = (const float*)d_in[0];
    const float* labels  = (const float*)d_in[1];
    float* acc = (float*)d_ws;   // [0]obj [1]szs [2]offs [3]cls [4+3b..] tp,fp,fn

    hipMemsetAsync(acc, 0, (4 + 3 * NB) * sizeof(float), stream);
    yolo_main<<<NB * BPI, TPB, 0, stream>>>(outputs, labels, acc);
    yolo_fin<<<1, 64, 0, stream>>>(acc, (float*)d_out);
}

// Round 7
// 222.486 us; speedup vs baseline: 1.0576x; 1.0062x over previous
//
#include <hip/hip_runtime.h>
#include <math.h>

#define NB    16        // batch
#define NC    25        // channels
#define HW    65536     // 256*256
#define CHW   (NC * HW)
#define EPSF  1e-8f
#define TPB   256       // 4 waves
#define BPI   64        // blocks per image; slab = 1024 px
#define SLAB  1024
#define GR    5         // channels per staged group
#define NGRP  5         // 25 channels = 5 groups

union F4 { float4 v; float a[4]; };

typedef const float __attribute__((address_space(1)))* gp_t;  // global
typedef float       __attribute__((address_space(3)))* lp_t;  // LDS

__device__ __forceinline__ float wave_reduce(float v) {
#pragma unroll
    for (int o = 32; o > 0; o >>= 1) v += __shfl_down(v, o, 64);
    return v;
}

// R7: async global->LDS staging. R1-R6 all pinned at ~2.6 TB/s effective
// because the register allocator refuses >2-3 outstanding loads/wave (VGPR
// evidence: 44 vs the ~120 a depth-4 ring needs). global_load_lds puts
// 40 x 1KB loads in flight per block with zero VGPR cost and the compiler
// cannot sink them. m97-style 2-barrier double-buffer; 80KB LDS -> 2
// blocks/CU whose alternation covers each other's barrier drain.
__global__ __launch_bounds__(TPB) void yolo_main(const float* __restrict__ outputs,
                                                 const float* __restrict__ labels,
                                                 float* __restrict__ acc) {
    __shared__ float lds[2][2 * GR][SLAB];   // [buf][stream: 2*ci+{0=out,1=lab}][pixel]

    const int b    = blockIdx.x / BPI;
    const int slab = blockIdx.x % BPI;
    const size_t base = (size_t)b * CHW + (size_t)slab * SLAB;
    const int wv   = threadIdx.x >> 6;       // wave id 0..3 (uniform per wave)
    const int lane = threadIdx.x & 63;
    const int t4   = threadIdx.x * 4;        // consume offset (floats)

    // per-lane global pointers for this wave's 1KB quarter of each stream
    const float* og = outputs + base + wv * 256 + lane * 4;
    const float* lg = labels  + base + wv * 256 + lane * 4;

    float y0[4], vmax[4], vout[4];
    float obj = 0.f, szs = 0.f, offs = 0.f, cls = 0.f;
    float tp = 0.f, fp = 0.f, fn = 0.f;
#pragma unroll
    for (int i = 0; i < 4; ++i) { vmax[i] = -1.0f; vout[i] = 0.0f; }

    // stage group g (channels g*GR .. g*GR+4) into buffer bf:
    // each wave issues 10 async 16B/lane loads (1KB each), LDS base wave-uniform.
    auto stage = [&](int g, int bf) {
#pragma unroll
        for (int ci = 0; ci < GR; ++ci) {
            const size_t choff = (size_t)(g * GR + ci) * HW;
            __builtin_amdgcn_global_load_lds((gp_t)(og + choff),
                                             (lp_t)&lds[bf][2 * ci + 0][wv * 256], 16, 0, 0);
            __builtin_amdgcn_global_load_lds((gp_t)(lg + choff),
                                             (lp_t)&lds[bf][2 * ci + 1][wv * 256], 16, 0, 0);
        }
    };

    stage(0, 0);

#pragma unroll
    for (int g = 0; g < NGRP; ++g) {
        if (g + 1 < NGRP) stage(g + 1, (g + 1) & 1);
        __syncthreads();                      // drains vmcnt: group g (and g+1) landed
        const int bf = g & 1;

        if (g == 0) {
            // ---- channels 0..4: BCE + F1 + size/offset L1
            F4 x, y;
            x.v = *(const float4*)&lds[bf][0][t4];
            y.v = *(const float4*)&lds[bf][1][t4];
#pragma unroll
            for (int i = 0; i < 4; ++i) {
                float xv = x.a[i], yv = y.a[i];
                float xc = fminf(fmaxf(xv,        EPSF), 1.0f - EPSF);
                float x1 = fminf(fmaxf(1.0f - xv, EPSF), 1.0f - EPSF);
                obj += -yv * (1.0f - xc) * __logf(xc)
                       - (1.0f - yv) * (1.0f - x1) * __logf(x1);
                float p  = (xv > 0.5f) ? 1.f : 0.f;
                float yt = (yv > 0.5f) ? 1.f : 0.f;
                tp += p * yt;
                fp += p * (1.f - yt);
                fn += (1.f - p) * yt;
                y0[i] = yv;
            }
#pragma unroll
            for (int ci = 1; ci <= 4; ++ci) {
                F4 o, l;
                o.v = *(const float4*)&lds[bf][2 * ci + 0][t4];
                l.v = *(const float4*)&lds[bf][2 * ci + 1][t4];
                float s = 0.f;
#pragma unroll
                for (int i = 0; i < 4; ++i) s += y0[i] * fabsf(o.a[i] - l.a[i]);
                if (ci <= 2) szs += s; else offs += s;
            }
        } else {
            // ---- channels 5..24: argmax(labels) carrying outputs
            // ascending channel order + strict > = argmax first-index tie-break
#pragma unroll
            for (int ci = 0; ci < GR; ++ci) {
                F4 o, l;
                o.v = *(const float4*)&lds[bf][2 * ci + 0][t4];
                l.v = *(const float4*)&lds[bf][2 * ci + 1][t4];
#pragma unroll
                for (int i = 0; i < 4; ++i) {
                    if (l.a[i] > vmax[i]) { vmax[i] = l.a[i]; vout[i] = o.a[i]; }
                }
            }
        }
        __syncthreads();                      // buffer reusable
    }

#pragma unroll
    for (int i = 0; i < 4; ++i) cls += y0[i] * (-vout[i]);

    // ---- block reduction: 7 values
    obj  = wave_reduce(obj);
    szs  = wave_reduce(szs);
    offs = wave_reduce(offs);
    cls  = wave_reduce(cls);
    tp   = wave_reduce(tp);
    fp   = wave_reduce(fp);
    fn   = wave_reduce(fn);

    __shared__ float sm[TPB / 64][7];
    if (lane == 0) {
        sm[wv][0] = obj;  sm[wv][1] = szs; sm[wv][2] = offs;
        sm[wv][3] = cls;  sm[wv][4] = tp;  sm[wv][5] = fp;  sm[wv][6] = fn;
    }
    __syncthreads();
    if (threadIdx.x < 7) {
        float s = 0.f;
#pragma unroll
        for (int w = 0; w < TPB / 64; ++w) s += sm[w][threadIdx.x];
        if (threadIdx.x < 4) atomicAdd(&acc[threadIdx.x], s);
        else                 atomicAdd(&acc[4 + 3 * b + (threadIdx.x - 4)], s);
    }
}

__global__ void yolo_fin(const float* __restrict__ acc, float* __restrict__ out) {
    if (threadIdx.x == 0) {
        float obj = acc[0];
        float sz  = 0.1f * acc[1];
        float off = 0.1f * acc[2];
        float cls = acc[3];
        float f1 = 0.f;
        for (int b = 0; b < NB; ++b) {
            float tp = acc[4 + 3 * b], fp = acc[5 + 3 * b], fn = acc[6 + 3 * b];
            float den = 2.f * tp + fp + fn;
            f1 += (den > 0.f) ? (2.f * tp) / fmaxf(den, 1.f) : 0.f;
        }
        f1 *= (1.0f / NB);
        out[0] = obj + sz + off + cls;
        out[1] = f1;
        out[2] = obj;
        out[3] = sz;
        out[4] = off;
        out[5] = cls;
    }
}

extern "C" void kernel_launch(void* const* d_in, const int* in_sizes, int n_in,
                              void* d_out, int out_size, void* d_ws, size_t ws_size,
                              hipStream_t stream) {
    const float* outputs = (const float*)d_in[0];
    const float* labels  = (const float*)d_in[1];
    float* acc = (float*)d_ws;   // [0]obj [1]szs [2]offs [3]cls [4+3b..] tp,fp,fn

    hipMemsetAsync(acc, 0, (4 + 3 * NB) * sizeof(float), stream);
    yolo_main<<<NB * BPI, TPB, 0, stream>>>(outputs, labels, acc);
    yolo_fin<<<1, 64, 0, stream>>>(acc, (float*)d_out);
}